// Round 1
// baseline (376.967 us; speedup 1.0000x reference)
//
#include <hip/hip_runtime.h>

#define BATCH 16
#define NBG   60     // NB: spatial grid per angle
#define LMAX  30     // degrees l = 0..29
#define MWC   59     // centered freq width, m in [-29,29]
#define CTR   29
#define NPAIR 20     // ch_in * ch_out for both stages
#define PI_D  3.14159265358979323846

// ---------------------------------------------------------------------------
// Wigner small-d column: d^l_{mp,mn}(beta) for l = 0..29 (zero below lmin),
// via Jacobi-polynomial recurrence, f64. Standard convention
// d^l = exp(-i beta Jy)  ==  expm(-(beta/2)(J+ - J-)) (matches reference).
// d^l_{mp,mn} = eps * sqrt(s!(s+a+b)!/((s+a)!(s+b)!)) * sin(b/2)^a cos(b/2)^b
//               * P_s^{(a,b)}(cos beta),
// a=|mp-mn|, b=|mp+mn|, s=l-max(|mp|,|mn|), eps=(-1)^{mp-mn} if mp>=mn else +1
// ---------------------------------------------------------------------------
__device__ __forceinline__ void wigner_col(double beta, int mp, int mn,
                                           float* out, int stride) {
  int a = mp - mn; if (a < 0) a = -a;
  int b = mp + mn; if (b < 0) b = -b;
  int lmin = (a + b) >> 1;
  for (int l = 0; l < LMAX; ++l) out[l * stride] = 0.0f;
  if (lmin >= LMAX) return;
  double x  = cos(beta);
  double sh = sin(0.5 * beta), ch = cos(0.5 * beta);
  double base = 1.0;
  for (int t = 0; t < a; ++t) base *= sh;
  for (int t = 0; t < b; ++t) base *= ch;
  if (mp >= mn && ((mp - mn) & 1)) base = -base;
  double K2 = 1.0;                               // K2(0) = C(a+b, a)
  for (int t = 1; t <= a; ++t) K2 *= (double)(b + t) / (double)t;
  double Pm2 = 0.0, Pm1 = 1.0;                   // P_0 = 1
  out[lmin * stride] = (float)(base * sqrt(K2));
  for (int s = 1; lmin + s < LMAX; ++s) {
    double Ps;
    if (s == 1) {
      Ps = (a + 1) + (a + b + 2) * 0.5 * (x - 1.0);
    } else {
      double t0 = 2.0 * s + a + b;
      double c1 = 2.0 * s * (s + a + b) * (t0 - 2.0);
      double c2 = (t0 - 1.0) * (t0 * (t0 - 2.0) * x + (double)(a * a - b * b));
      double c3 = 2.0 * (s + a - 1.0) * (s + b - 1.0) * t0;
      Ps = (c2 * Pm1 - c3 * Pm2) / c1;
    }
    K2 *= ((double)s * (s + a + b)) / (((double)s + a) * ((double)s + b));
    out[(lmin + s) * stride] = (float)(base * sqrt(K2) * Ps);
    Pm2 = Pm1; Pm1 = Ps;
  }
}

// ---------------------------------------------------------------------------
// K0: small constant tables.
//  wq[60]      : S3 quadrature weights over beta
//  wqn[59]     : wqn[N] = sum_g wq[g] e^{+2pi i (N-29) g / 60}
//  cwE1/2[p,N] : conj(wE) = sum_p w[pair,p] e^{+i (N-29) * 2pi p/6}
// ---------------------------------------------------------------------------
__global__ void k_tables(const float* __restrict__ w_conv,
                         const float* __restrict__ w_deconv,
                         float* __restrict__ wq, float2* __restrict__ wqn,
                         float2* __restrict__ cwE1, float2* __restrict__ cwE2) {
  int t = threadIdx.x;  // blockDim = 128
  if (t < NBG) {
    double j = t, s = 0.0;
    for (int k = 0; k < 30; ++k)
      s += sin(PI_D * (2.0 * j + 1.0) * (2.0 * k + 1.0) / 120.0) / (2.0 * k + 1.0);
    wq[t] = (float)((2.0 / 30.0) * sin(PI_D * (2.0 * j + 1.0) / 120.0) * s);
  }
  __syncthreads();
  if (t < MWC) {
    int n = t - CTR;
    double re = 0.0, im = 0.0;
    for (int g = 0; g < NBG; ++g) {
      double sn, cs; sincos(2.0 * PI_D * n * g / 60.0, &sn, &cs);
      re += (double)wq[g] * cs; im += (double)wq[g] * sn;
    }
    wqn[t] = make_float2((float)re, (float)im);
  }
  for (int idx = t; idx < NPAIR * MWC; idx += blockDim.x) {
    int pair = idx / MWC, N = idx % MWC, n = N - CTR;
    double re1 = 0, im1 = 0, re2 = 0, im2 = 0;
    for (int p = 0; p < 6; ++p) {
      double sn, cs; sincos((double)n * (2.0 * PI_D * p / 6.0), &sn, &cs);
      re1 += (double)w_conv[pair * 6 + p] * cs;  im1 += (double)w_conv[pair * 6 + p] * sn;
      re2 += (double)w_deconv[pair * 6 + p] * cs; im2 += (double)w_deconv[pair * 6 + p] * sn;
    }
    cwE1[idx] = make_float2((float)re1, (float)im1);
    cwE2[idx] = make_float2((float)re2, (float)im2);
  }
}

// ---------------------------------------------------------------------------
// K1: n=0 Wigner columns.  blocks 0..59 -> D0[j][l][M] = d^l_{M-29,0}(beta_j)
//     block 60            -> dk[l][M]   = d^l_{M-29,0}(pi/160)
// ---------------------------------------------------------------------------
__global__ void k_wigner0(float* __restrict__ D0, float* __restrict__ dkn) {
  int bi = blockIdx.x;
  int M = threadIdx.x;
  if (M >= MWC) return;
  double beta = (bi < NBG) ? PI_D * (2.0 * bi + 1.0) / 120.0 : PI_D / 160.0;
  if (bi < NBG) wigner_col(beta, M - CTR, 0, D0 + (size_t)bi * LMAX * MWC + M, MWC);
  else          wigner_col(beta, M - CTR, 0, dkn + M, MWC);
}

// ---------------------------------------------------------------------------
// K2: DFT over alpha -> centered m.  One block per row (b*ci*60 rows).
// xfc[row][M] = (2pi/60) * sum_a x[row][a] e^{-2pi i (M-29) a / 60}
// ---------------------------------------------------------------------------
__global__ void k_fft_alpha(const float* __restrict__ xin, float2* __restrict__ xfc) {
  __shared__ float xr[NBG];
  __shared__ float twc[NBG], tws[NBG];
  int r = blockIdx.x, t = threadIdx.x;
  if (t < NBG) {
    xr[t] = xin[(size_t)r * NBG + t];
    float s, c; sincosf(-2.0f * (float)PI_D * t / 60.0f, &s, &c);
    twc[t] = c; tws[t] = s;
  }
  __syncthreads();
  if (t < MWC) {
    int mm = t - CTR;
    float re = 0.f, im = 0.f; int k = 0;
    for (int a = 0; a < NBG; ++a) {
      re += xr[a] * twc[k]; im += xr[a] * tws[k];
      k += mm; if (k >= NBG) k -= NBG; if (k < 0) k += NBG;
    }
    const float sc = 2.0f * (float)PI_D / 60.0f;
    xfc[(size_t)r * MWC + t] = make_float2(re * sc, im * sc);
  }
}

// ---------------------------------------------------------------------------
// K3: S2 analysis.  X[bi,l,M] = sum_j wq[j] * D0[j,l,M] * xfc[bi,j,M]
// ---------------------------------------------------------------------------
__global__ void k_analysis(const float2* __restrict__ xfc, const float* __restrict__ D0,
                           const float* __restrict__ wq, float2* __restrict__ X, int CI) {
  int idx = blockIdx.x * blockDim.x + threadIdx.x;
  int total = BATCH * CI * LMAX * MWC;
  if (idx >= total) return;
  int M = idx % MWC, l = (idx / MWC) % LMAX, bi = idx / (MWC * LMAX);
  float re = 0.f, im = 0.f;
  for (int j = 0; j < NBG; ++j) {
    float w = wq[j] * D0[((size_t)j * LMAX + l) * MWC + M];
    float2 v = xfc[((size_t)bi * NBG + j) * MWC + M];
    re += w * v.x; im += w * v.y;
  }
  X[idx] = make_float2(re, im);
}

// ---------------------------------------------------------------------------
// K45: the heavy fused contraction. One block per (j, M).
//  phase1: sg[l][N] = d^l_{m,n}(beta_j) * dk[l,N] * wqn[N]          (LDS)
//  phase2: Cg[pair][l] = sum_N sg[l][N] * cwE[pair][N]              (LDS)
//  phase3: T[b,o,j,M] = sum_l (2l+1) sum_i X[b,i,l,M] * Cg[i*CO+o][l]
// ---------------------------------------------------------------------------
template <int CI, int CO>
__global__ __launch_bounds__(256) void k_core(const float2* __restrict__ X,
                                              const float* __restrict__ dkn,
                                              const float2* __restrict__ wqn,
                                              const float2* __restrict__ cwE,
                                              float2* __restrict__ T) {
  __shared__ float sgRe[LMAX][NBG];
  __shared__ float sgIm[LMAX][NBG];
  __shared__ float2 sC[NPAIR * LMAX];
  __shared__ float2 scw[NPAIR * MWC];
  int blk = blockIdx.x;
  int j = blk / MWC, M = blk % MWC;
  int mp = M - CTR;
  int am = mp < 0 ? -mp : mp;
  int t = threadIdx.x;
  for (int i = t; i < NPAIR * MWC; i += 256) scw[i] = cwE[i];
  if (t < MWC) {
    double beta = PI_D * (2.0 * j + 1.0) / 120.0;
    wigner_col(beta, mp, t - CTR, &sgRe[0][t], NBG);  // raw d into sgRe column
    float2 w = wqn[t];
    for (int l = 0; l < LMAX; ++l) {
      float v = sgRe[l][t] * dkn[l * MWC + t];
      sgRe[l][t] = v * w.x;
      sgIm[l][t] = v * w.y;
    }
  }
  __syncthreads();
  for (int o = t; o < NPAIR * LMAX; o += 256) {
    int pair = o / LMAX, l = o % LMAX;
    float cre = 0.f, cim = 0.f;
    if (l >= am) {
      int N0 = CTR - l, N1 = CTR + l;
      for (int N = N0; N <= N1; ++N) {
        float2 cw = scw[pair * MWC + N];
        float gr = sgRe[l][N], gi = sgIm[l][N];
        cre += gr * cw.x - gi * cw.y;
        cim += gr * cw.y + gi * cw.x;
      }
    }
    sC[o] = make_float2(cre, cim);
  }
  __syncthreads();
  for (int u = t; u < BATCH * CO; u += 256) {
    int bb = u / CO, o = u % CO;
    float tre = 0.f, tim = 0.f;
    for (int i = 0; i < CI; ++i) {
      const float2* Xp = X + ((size_t)(bb * CI + i) * LMAX) * MWC + M;
      const float2* Cp = sC + (i * CO + o) * LMAX;
      for (int l = am; l < LMAX; ++l) {
        float fac = (float)(2 * l + 1);
        float2 xv = Xp[(size_t)l * MWC];
        float2 cv = Cp[l];
        tre += fac * (xv.x * cv.x - xv.y * cv.y);
        tim += fac * (xv.x * cv.y + xv.y * cv.x);
      }
    }
    T[((size_t)u * NBG + j) * MWC + M] = make_float2(tre, tim);
  }
}

// ---------------------------------------------------------------------------
// K6: inverse DFT over alpha (real part). One block per row (b*co*60 rows).
// y[row][a] = Re( sum_M T[row][M] e^{+2pi i (M-29) a / 60} )
// ---------------------------------------------------------------------------
__global__ void k_synth_alpha(const float2* __restrict__ T, float* __restrict__ yout) {
  __shared__ float2 Tr[MWC];
  __shared__ float twc[NBG], tws[NBG];
  int r = blockIdx.x, t = threadIdx.x;
  if (t < MWC) Tr[t] = T[(size_t)r * MWC + t];
  if (t < NBG) {
    float s, c; sincosf(2.0f * (float)PI_D * t / 60.0f, &s, &c);
    twc[t] = c; tws[t] = s;
  }
  __syncthreads();
  if (t < NBG) {
    float acc = 0.f;
    for (int Mi = 0; Mi < MWC; ++Mi) {
      int mm = Mi - CTR;
      int k = (mm * t) % NBG; if (k < 0) k += NBG;
      float2 v = Tr[Mi];
      acc += v.x * twc[k] - v.y * tws[k];
    }
    yout[(size_t)r * NBG + t] = acc;
  }
}

// ---------------------------------------------------------------------------
extern "C" void kernel_launch(void* const* d_in, const int* in_sizes, int n_in,
                              void* d_out, int out_size, void* d_ws, size_t ws_size,
                              hipStream_t stream) {
  const float* x1       = (const float*)d_in[0];
  const float* w_conv   = (const float*)d_in[1];
  const float* w_deconv = (const float*)d_in[2];
  float* out = (float*)d_out;
  char* ws = (char*)d_ws;

  // workspace layout (bytes, 256-aligned); T aliases xfc (xfc dead after K3)
  float*  wq   = (float*) (ws + 0);         //   60 f32
  float2* wqn  = (float2*)(ws + 256);       //   59 c64
  float2* cwE1 = (float2*)(ws + 768);       // 1180 c64
  float2* cwE2 = (float2*)(ws + 10240);     // 1180 c64
  float*  dkn  = (float*) (ws + 19712);     // 30*59 f32
  float*  D0   = (float*) (ws + 26880);     // 60*30*59 f32
  float2* xfc  = (float2*)(ws + 451712);    // 16*10*60*59 c64 (max stage)
  float2* T    = (float2*)(ws + 451712);    // alias of xfc
  float2* X    = (float2*)(ws + 4982912);   // 16*10*30*59 c64
  float*  y    = (float*) (ws + 7248512);   // 16*10*60*60 f32
  // total ~9.56 MB

  k_tables<<<1, 128, 0, stream>>>(w_conv, w_deconv, wq, wqn, cwE1, cwE2);
  k_wigner0<<<NBG + 1, 64, 0, stream>>>(D0, dkn);

  // ---- stage 1: encode (ci=2 -> co=10), input x1, output y (gamma-integrated)
  {
    const int CI = 2, CO = 10;
    k_fft_alpha<<<BATCH * CI * NBG, 64, 0, stream>>>(x1, xfc);
    int tot = BATCH * CI * LMAX * MWC;
    k_analysis<<<(tot + 255) / 256, 256, 0, stream>>>(xfc, D0, wq, X, CI);
    k_core<2, 10><<<NBG * MWC, 256, 0, stream>>>(X, dkn, wqn, cwE1, T);
    k_synth_alpha<<<BATCH * CO * NBG, 64, 0, stream>>>(T, y);
  }
  // ---- stage 2: decode (ci=10 -> co=2), input y, output d_out
  {
    const int CI = 10, CO = 2;
    k_fft_alpha<<<BATCH * CI * NBG, 64, 0, stream>>>(y, xfc);
    int tot = BATCH * CI * LMAX * MWC;
    k_analysis<<<(tot + 255) / 256, 256, 0, stream>>>(xfc, D0, wq, X, CI);
    k_core<10, 2><<<NBG * MWC, 256, 0, stream>>>(X, dkn, wqn, cwE2, T);
    k_synth_alpha<<<BATCH * CO * NBG, 64, 0, stream>>>(T, out);
  }
}

// Round 2
// 336.771 us; speedup vs baseline: 1.1194x; 1.1194x over previous
//
#include <hip/hip_runtime.h>

#define BATCH 16
#define NBG   60     // spatial grid per angle
#define LMAX  30     // degrees l = 0..29
#define MWC   59     // centered freq width, m in [-29,29]
#define CTR   29
#define NPAIR 20     // ch_in * ch_out (both stages)
#define PI_D  3.14159265358979323846

// ---------------------------------------------------------------------------
// f32 Wigner small-d column d^l_{mp,mn}(beta), l=0..29 (zeros below lmin),
// Jacobi recurrence. Convention == expm(-(beta/2)(J+ - J-)) (verified r1).
// ---------------------------------------------------------------------------
__device__ void wigner_colf(float beta, int mp, int mn, float* out, int stride) {
  int a = mp - mn; if (a < 0) a = -a;
  int b = mp + mn; if (b < 0) b = -b;
  int lmin = (a + b) >> 1;
  for (int l = 0; l < LMAX; ++l) out[l * stride] = 0.0f;
  if (lmin >= LMAX) return;
  float sh, ch; sincosf(0.5f * beta, &sh, &ch);
  float x = ch * ch - sh * sh;
  float base = 1.f;
  for (int q = 0; q < a; ++q) base *= sh;
  for (int q = 0; q < b; ++q) base *= ch;
  if (mp >= mn && ((mp - mn) & 1)) base = -base;
  float K2 = 1.f;
  for (int q = 1; q <= a; ++q) K2 *= (float)(b + q) / (float)q;
  float Pm2 = 0.f, Pm1 = 1.f;
  out[lmin * stride] = base * sqrtf(K2);
  for (int s = 1; lmin + s < LMAX; ++s) {
    float Ps;
    if (s == 1) {
      Ps = (a + 1) + (a + b + 2) * 0.5f * (x - 1.f);
    } else {
      float t0 = 2.f * s + a + b;
      float c1 = 2.f * s * (s + a + b) * (t0 - 2.f);
      float c2 = (t0 - 1.f) * (t0 * (t0 - 2.f) * x + (float)(a * a - b * b));
      float c3 = 2.f * (s + a - 1.f) * (s + b - 1.f) * t0;
      Ps = (c2 * Pm1 - c3 * Pm2) / c1;
    }
    K2 *= ((float)s * (s + a + b)) / (((float)s + a) * ((float)s + b));
    out[(lmin + s) * stride] = base * sqrtf(K2) * Ps;
    Pm2 = Pm1; Pm1 = Ps;
  }
}

// ---------------------------------------------------------------------------
// K_prep (grid 62 x 128):
//  block 0      : wq[60], wqn[59], cwT1/cwT2 [N][pair] (transposed, conj'd)
//  block 1      : dkn[l][N] = d^l_{N-29,0}(pi/160)
//  blocks 2..61 : D0[j][l][M] = d^l_{M-29,0}(beta_j)
// ---------------------------------------------------------------------------
__global__ void k_prep(const float* __restrict__ w_conv, const float* __restrict__ w_deconv,
                       float* __restrict__ wq, float2* __restrict__ wqn,
                       float2* __restrict__ cwT1, float2* __restrict__ cwT2,
                       float* __restrict__ dkn, float* __restrict__ D0) {
  __shared__ float swq[NBG];
  int bi = blockIdx.x, t = threadIdx.x;
  if (bi == 0) {
    if (t < NBG) {
      float s = 0.f;
      for (int k = 0; k < 30; ++k)
        s += sinf((float)(PI_D * (2.0 * t + 1.0) * (2.0 * k + 1.0) / 120.0)) / (float)(2 * k + 1);
      float v = (2.f / 30.f) * sinf((float)(PI_D * (2.0 * t + 1.0) / 120.0)) * s;
      swq[t] = v; wq[t] = v;
    }
    __syncthreads();
    if (t < MWC) {
      int n = t - CTR;
      float re = 0.f, im = 0.f;
      for (int g = 0; g < NBG; ++g) {
        float sn, cs; sincosf((float)(2.0 * PI_D * (double)(n * g) / 60.0), &sn, &cs);
        re += swq[g] * cs; im += swq[g] * sn;
      }
      wqn[t] = make_float2(re, im);
    }
    for (int idx = t; idx < NPAIR * MWC; idx += blockDim.x) {
      int pair = idx / MWC, N = idx - pair * MWC, n = N - CTR;
      float re1 = 0, im1 = 0, re2 = 0, im2 = 0;
      for (int p = 0; p < 6; ++p) {
        float sn, cs; sincosf((float)((double)n * (2.0 * PI_D * p / 6.0)), &sn, &cs);
        float a1 = w_conv[pair * 6 + p], a2 = w_deconv[pair * 6 + p];
        re1 += a1 * cs; im1 += a1 * sn;
        re2 += a2 * cs; im2 += a2 * sn;
      }
      cwT1[N * NPAIR + pair] = make_float2(re1, im1);
      cwT2[N * NPAIR + pair] = make_float2(re2, im2);
    }
  } else if (bi == 1) {
    if (t < MWC) wigner_colf((float)(PI_D / 160.0), t - CTR, 0, dkn + t, MWC);
  } else {
    int j = bi - 2;
    if (t < MWC)
      wigner_colf((float)(PI_D * (2.0 * j + 1.0) / 120.0), t - CTR, 0,
                  D0 + (size_t)j * LMAX * MWC + t, MWC);
  }
}

// ---------------------------------------------------------------------------
// K2: DFT over alpha -> centered m. One block (64 thr) per row.
// ---------------------------------------------------------------------------
__global__ void k_fft_alpha(const float* __restrict__ xin, float2* __restrict__ xfc) {
  __shared__ float xr[NBG];
  __shared__ float twc[NBG], tws[NBG];
  int r = blockIdx.x, t = threadIdx.x;
  if (t < NBG) {
    xr[t] = xin[(size_t)r * NBG + t];
    float s, c; sincosf(-2.0f * (float)PI_D * t / 60.0f, &s, &c);
    twc[t] = c; tws[t] = s;
  }
  __syncthreads();
  if (t < MWC) {
    int mm = t - CTR;
    float re = 0.f, im = 0.f; int k = 0;
    for (int a = 0; a < NBG; ++a) {
      re += xr[a] * twc[k]; im += xr[a] * tws[k];
      k += mm; if (k >= NBG) k -= NBG; if (k < 0) k += NBG;
    }
    const float sc = 2.0f * (float)PI_D / 60.0f;
    xfc[(size_t)r * MWC + t] = make_float2(re * sc, im * sc);
  }
}

// ---------------------------------------------------------------------------
// K3: S2 analysis. X[bi,l,M] = sum_j wq[j] D0[j,l,M] xfc[bi,j,M]
// ---------------------------------------------------------------------------
__global__ void k_analysis(const float2* __restrict__ xfc, const float* __restrict__ D0,
                           const float* __restrict__ wq, float2* __restrict__ X, int CI) {
  int idx = blockIdx.x * blockDim.x + threadIdx.x;
  int total = BATCH * CI * LMAX * MWC;
  if (idx >= total) return;
  int M = idx % MWC, l = (idx / MWC) % LMAX, bi = idx / (MWC * LMAX);
  float re = 0.f, im = 0.f;
  for (int j = 0; j < NBG; ++j) {
    float w = wq[j] * D0[((size_t)j * LMAX + l) * MWC + M];
    float2 v = xfc[((size_t)bi * NBG + j) * MWC + M];
    re += w * v.x; im += w * v.y;
  }
  X[idx] = make_float2(re, im);
}

// ---------------------------------------------------------------------------
// K45: fused core, one 64-thread block per (j, M).
//  phase1: lane N: f32 Wigner column over l -> sg[l][N] = d*dk[l,N]*wqn[N]
//  phase2: C[pair][l] = (2l+1) * sum_N sg[l][N]*cwT[N][pair]   (LDS->LDS)
//  phase3: T[jm][u]   = sum_i sum_l X[b,i,l,M]*C[i*CO+o][l]    (T layout [jm][u])
// ---------------------------------------------------------------------------
template <int CI, int CO>
__global__ __launch_bounds__(64) void k_core(const float2* __restrict__ X,
                                             const float* __restrict__ dkn,
                                             const float2* __restrict__ wqn,
                                             const float2* __restrict__ cwT,
                                             float2* __restrict__ T) {
  constexpr int UU = BATCH * CO;
  __shared__ float2 sg[LMAX][MWC];      // 14160 B
  __shared__ float2 sC[NPAIR][LMAX];    //  4800 B
  __shared__ float2 scw[NPAIR * MWC];   //  9440 B
  int t = threadIdx.x;
  int jm = blockIdx.x;
  int j = jm / MWC, M = jm - j * MWC;
  int mp = M - CTR;
  int am = mp < 0 ? -mp : mp;

  for (int q = t; q < NPAIR * MWC; q += 64) scw[q] = cwT[q];

  if (t < MWC) {
    int N = t, mn = N - CTR;
    float2 w = wqn[N];
    for (int l = 0; l < LMAX; ++l) sg[l][N] = make_float2(0.f, 0.f);
    int a = mp - mn; if (a < 0) a = -a;
    int b = mp + mn; if (b < 0) b = -b;
    int lmin = (a + b) >> 1;
    if (lmin < LMAX) {
      float beta = (float)(PI_D * (2.0 * j + 1.0) / 120.0);
      float sh, ch; sincosf(0.5f * beta, &sh, &ch);
      float x = ch * ch - sh * sh;
      float base = 1.f;
      for (int q = 0; q < a; ++q) base *= sh;
      for (int q = 0; q < b; ++q) base *= ch;
      if (mp >= mn && ((mp - mn) & 1)) base = -base;
      float K2 = 1.f;
      for (int q = 1; q <= a; ++q) K2 *= (float)(b + q) / (float)q;
      float Pm2 = 0.f, Pm1 = 1.f;
      {
        float v = base * sqrtf(K2) * dkn[lmin * MWC + N];
        sg[lmin][N] = make_float2(v * w.x, v * w.y);
      }
      for (int s = 1; lmin + s < LMAX; ++s) {
        float Ps;
        if (s == 1) {
          Ps = (a + 1) + (a + b + 2) * 0.5f * (x - 1.f);
        } else {
          float t0 = 2.f * s + a + b;
          float c1 = 2.f * s * (s + a + b) * (t0 - 2.f);
          float c2 = (t0 - 1.f) * (t0 * (t0 - 2.f) * x + (float)(a * a - b * b));
          float c3 = 2.f * (s + a - 1.f) * (s + b - 1.f) * t0;
          Ps = (c2 * Pm1 - c3 * Pm2) / c1;
        }
        K2 *= ((float)s * (s + a + b)) / (((float)s + a) * ((float)s + b));
        float v = base * sqrtf(K2) * Ps * dkn[(lmin + s) * MWC + N];
        sg[lmin + s][N] = make_float2(v * w.x, v * w.y);
        Pm2 = Pm1; Pm1 = Ps;
      }
    }
  }
  __syncthreads();

  // phase 2: q = l*20 + pair  (wave spans <=2 l values -> balanced trips)
  for (int q = t; q < NPAIR * LMAX; q += 64) {
    int l = q / NPAIR, pair = q - l * NPAIR;
    float cre = 0.f, cim = 0.f;
    if (l >= am) {
      for (int N = CTR - l; N <= CTR + l; ++N) {
        float2 g = sg[l][N];
        float2 c = scw[N * NPAIR + pair];
        cre += g.x * c.x - g.y * c.y;
        cim += g.x * c.y + g.y * c.x;
      }
    }
    float fac = (float)(2 * l + 1);
    sC[pair][l] = make_float2(fac * cre, fac * cim);
  }
  __syncthreads();

  // phase 3
  if constexpr (UU >= 64) {
    for (int u = t; u < UU; u += 64) {
      int bb = u / CO, o = u - bb * CO;
      float tre = 0.f, tim = 0.f;
      for (int i = 0; i < CI; ++i) {
        const float2* Xp = X + ((size_t)(bb * CI + i) * LMAX + am) * MWC + M;
        const float2* Cp = &sC[i * CO + o][am];
        for (int l = am; l < LMAX; ++l) {
          float2 xv = *Xp; Xp += MWC;
          float2 cv = *Cp; ++Cp;
          tre += xv.x * cv.x - xv.y * cv.y;
          tim += xv.x * cv.y + xv.y * cv.x;
        }
      }
      T[(size_t)jm * UU + u] = make_float2(tre, tim);
    }
  } else {
    // UU=32: split l-loop across two half-waves, shfl-reduce
    int u = t & (UU - 1), sub = t / UU;
    int bb = u / CO, o = u - bb * CO;
    float tre = 0.f, tim = 0.f;
    for (int i = 0; i < CI; ++i) {
      const float2* Xp = X + ((size_t)(bb * CI + i) * LMAX) * MWC + M;
      const float2* Cp = &sC[i * CO + o][0];
      for (int l = am + sub; l < LMAX; l += 2) {
        float2 xv = Xp[(size_t)l * MWC];
        float2 cv = Cp[l];
        tre += xv.x * cv.x - xv.y * cv.y;
        tim += xv.x * cv.y + xv.y * cv.x;
      }
    }
    tre += __shfl_xor(tre, 32);
    tim += __shfl_xor(tim, 32);
    if (sub == 0) T[(size_t)jm * UU + u] = make_float2(tre, tim);
  }
}

// ---------------------------------------------------------------------------
// K6: inverse DFT over alpha (real part). Block per row r = u*60 + j.
// T layout [jm][u] -> gathered read, coalesced everything else.
// ---------------------------------------------------------------------------
template <int UU>
__global__ void k_synth_alpha(const float2* __restrict__ T, float* __restrict__ yout) {
  __shared__ float2 Tr[MWC];
  __shared__ float twc[NBG], tws[NBG];
  int r = blockIdx.x, t = threadIdx.x;
  int u = r / NBG, j = r - u * NBG;
  if (t < MWC) Tr[t] = T[(size_t)(j * MWC + t) * UU + u];
  if (t < NBG) {
    float s, c; sincosf(2.0f * (float)PI_D * t / 60.0f, &s, &c);
    twc[t] = c; tws[t] = s;
  }
  __syncthreads();
  if (t < NBG) {
    float acc = 0.f;
    for (int Mi = 0; Mi < MWC; ++Mi) {
      int mm = Mi - CTR;
      int k = (mm * t) % NBG; if (k < 0) k += NBG;
      float2 v = Tr[Mi];
      acc += v.x * twc[k] - v.y * tws[k];
    }
    yout[(size_t)r * NBG + t] = acc;
  }
}

// ---------------------------------------------------------------------------
extern "C" void kernel_launch(void* const* d_in, const int* in_sizes, int n_in,
                              void* d_out, int out_size, void* d_ws, size_t ws_size,
                              hipStream_t stream) {
  const float* x1       = (const float*)d_in[0];
  const float* w_conv   = (const float*)d_in[1];
  const float* w_deconv = (const float*)d_in[2];
  float* out = (float*)d_out;
  char* ws = (char*)d_ws;

  // workspace layout (bytes); T aliases xfc (xfc dead after k_analysis)
  float*  wq   = (float*) (ws + 0);         //    60 f32
  float2* wqn  = (float2*)(ws + 256);       //    59 c64
  float2* cwT1 = (float2*)(ws + 768);       //  1180 c64 [N][pair]
  float2* cwT2 = (float2*)(ws + 10240);     //  1180 c64
  float*  dkn  = (float*) (ws + 19712);     // 30*59 f32
  float*  D0   = (float*) (ws + 26880);     // 60*30*59 f32
  float2* xfc  = (float2*)(ws + 451712);    // 16*10*60*59 c64
  float2* T    = (float2*)(ws + 451712);    // alias of xfc, layout [jm][u]
  float2* X    = (float2*)(ws + 4982912);   // 16*10*30*59 c64
  float*  y    = (float*) (ws + 7248512);   // 16*10*60*60 f32
  // total ~9.56 MB

  k_prep<<<NBG + 2, 128, 0, stream>>>(w_conv, w_deconv, wq, wqn, cwT1, cwT2, dkn, D0);

  // ---- stage 1: encode (ci=2 -> co=10)
  {
    const int CI = 2, CO = 10;
    k_fft_alpha<<<BATCH * CI * NBG, 64, 0, stream>>>(x1, xfc);
    int tot = BATCH * CI * LMAX * MWC;
    k_analysis<<<(tot + 255) / 256, 256, 0, stream>>>(xfc, D0, wq, X, CI);
    k_core<2, 10><<<NBG * MWC, 64, 0, stream>>>(X, dkn, wqn, cwT1, T);
    k_synth_alpha<160><<<BATCH * CO * NBG, 64, 0, stream>>>(T, y);
  }
  // ---- stage 2: decode (ci=10 -> co=2)
  {
    const int CI = 10, CO = 2;
    k_fft_alpha<<<BATCH * CI * NBG, 64, 0, stream>>>(y, xfc);
    int tot = BATCH * CI * LMAX * MWC;
    k_analysis<<<(tot + 255) / 256, 256, 0, stream>>>(xfc, D0, wq, X, CI);
    k_core<10, 2><<<NBG * MWC, 64, 0, stream>>>(X, dkn, wqn, cwT2, T);
    k_synth_alpha<32><<<BATCH * CO * NBG, 64, 0, stream>>>(T, out);
  }
}